// Round 1
// baseline (2252.807 us; speedup 1.0000x reference)
//
#include <hip/hip_runtime.h>

#define NEG_SLOPE 0.2f

constexpr int F = 512;    // heads * channels
constexpr int F_IN = 30;

// ---------------- CSR build ----------------

__global__ void hist_kernel(const int* __restrict__ ei, int* __restrict__ counts,
                            int N, int E) {
  int e = blockIdx.x * blockDim.x + threadIdx.x;
  int Et = E + N;
  if (e >= Et) return;
  int d = (e < E) ? ei[E + e] : (e - E);
  atomicAdd(&counts[d], 1);
}

__global__ void scan_kernel(const int* __restrict__ counts, int* __restrict__ offsets,
                            int* __restrict__ cursor, int n) {
  __shared__ int lds[1024];
  __shared__ int carry_s;
  if (threadIdx.x == 0) carry_s = 0;
  __syncthreads();
  for (int base = 0; base < n; base += 1024) {
    int i = base + threadIdx.x;
    int v = (i < n) ? counts[i] : 0;
    lds[threadIdx.x] = v;
    __syncthreads();
    for (int off = 1; off < 1024; off <<= 1) {
      int t = (threadIdx.x >= off) ? lds[threadIdx.x - off] : 0;
      __syncthreads();
      lds[threadIdx.x] += t;
      __syncthreads();
    }
    int excl = lds[threadIdx.x] - v;
    if (i < n) { int o = carry_s + excl; offsets[i] = o; cursor[i] = o; }
    __syncthreads();
    if (threadIdx.x == 1023) carry_s += lds[1023];
    __syncthreads();
  }
  if (threadIdx.x == 0) offsets[n] = carry_s;
}

__global__ void scatter_kernel(const int* __restrict__ ei, int* __restrict__ cursor,
                               int* __restrict__ src_s, int* __restrict__ dst_s,
                               int N, int E) {
  int e = blockIdx.x * blockDim.x + threadIdx.x;
  int Et = E + N;
  if (e >= Et) return;
  int s, d;
  if (e < E) { s = ei[e]; d = ei[E + e]; } else { s = e - E; d = e - E; }
  int p = atomicAdd(&cursor[d], 1);
  src_s[p] = s;
  dst_s[p] = d;
}

// ---------------- GEMM:  out[N,COLS] = X[N,K] @ W[K,COLS] ----------------
// block = 256 threads, 8 rows per block, each thread 2 columns (COLS = 512)

template <int K>
__global__ void gemm_kernel(const float* __restrict__ X, const float* __restrict__ W,
                            float* __restrict__ out, int N) {
  __shared__ float xs[8][K];
  int row0 = blockIdx.x * 8;
  int tid = threadIdx.x;
  for (int i = tid; i < 8 * K; i += 256) {
    int r = i / K, k = i - r * K;
    int row = row0 + r;
    xs[r][k] = (row < N) ? X[(size_t)row * K + k] : 0.f;
  }
  __syncthreads();
  int c0 = tid, c1 = tid + 256;
  float acc0[8], acc1[8];
#pragma unroll
  for (int r = 0; r < 8; ++r) { acc0[r] = 0.f; acc1[r] = 0.f; }
#pragma unroll 4
  for (int k = 0; k < K; ++k) {
    float w0 = W[(size_t)k * F + c0];
    float w1 = W[(size_t)k * F + c1];
#pragma unroll
    for (int r = 0; r < 8; ++r) {
      acc0[r] += xs[r][k] * w0;
      acc1[r] += xs[r][k] * w1;
    }
  }
#pragma unroll
  for (int r = 0; r < 8; ++r) {
    int row = row0 + r;
    if (row < N) {
      out[(size_t)row * F + c0] = acc0[r];
      out[(size_t)row * F + c1] = acc1[r];
    }
  }
}

// GEMM for layer3: out[N,4] = X[N,512] @ W3[512,4]; one wave per node
__global__ void gemm3_kernel(const float* __restrict__ X, const float* __restrict__ W3,
                             float* __restrict__ h3, int N) {
  int n = blockIdx.x * 4 + (threadIdx.x >> 6);
  int lane = threadIdx.x & 63;
  if (n >= N) return;
  float acc[4] = {0.f, 0.f, 0.f, 0.f};
  for (int k = lane; k < F; k += 64) {
    float xv = X[(size_t)n * F + k];
#pragma unroll
    for (int j = 0; j < 4; ++j) acc[j] += xv * W3[k * 4 + j];
  }
#pragma unroll
  for (int j = 0; j < 4; ++j)
    for (int off = 32; off > 0; off >>= 1) acc[j] += __shfl_down(acc[j], off);
  if (lane == 0) {
    float4 o; o.x = acc[0]; o.y = acc[1]; o.z = acc[2]; o.w = acc[3];
    *(float4*)(h3 + (size_t)n * 4) = o;
  }
}

// ---------------- alpha dots ----------------
// as[n,h] = sum_c h[n,h*128+c]*a_src[h*128+c]; block = 512 threads = 1 node

__global__ void alpha_kernel(const float* __restrict__ h, const float* __restrict__ asrc,
                             const float* __restrict__ adst, float* __restrict__ as,
                             float* __restrict__ ad) {
  int n = blockIdx.x;
  int tid = threadIdx.x;
  float hv = h[(size_t)n * F + tid];
  float ps = hv * asrc[tid];
  float pd = hv * adst[tid];
#pragma unroll
  for (int off = 32; off > 0; off >>= 1) {
    ps += __shfl_down(ps, off);
    pd += __shfl_down(pd, off);
  }
  __shared__ float ls[8], ld_[8];
  int wid = tid >> 6, lane = tid & 63;
  if (lane == 0) { ls[wid] = ps; ld_[wid] = pd; }
  __syncthreads();
  if (tid < 4) {
    as[n * 4 + tid] = ls[2 * tid] + ls[2 * tid + 1];
    ad[n * 4 + tid] = ld_[2 * tid] + ld_[2 * tid + 1];
  }
}

// layer3: C=1 -> as[n,h] = h3[n,h]*a3s[h]
__global__ void alpha3_kernel(const float* __restrict__ h3, const float* __restrict__ a3s,
                              const float* __restrict__ a3d, float* __restrict__ as,
                              float* __restrict__ ad, int N) {
  int t = blockIdx.x * blockDim.x + threadIdx.x;
  if (t >= N * 4) return;
  int hh = t & 3;
  float v = h3[t];
  as[t] = v * a3s[hh];
  ad[t] = v * a3d[hh];
}

// ---------------- edge scores (sorted order) ----------------

__device__ __forceinline__ float leaky(float v) { return v > 0.f ? v : NEG_SLOPE * v; }

__global__ void edge_score_kernel(const float* __restrict__ as, const float* __restrict__ ad,
                                  const int* __restrict__ src_s, const int* __restrict__ dst_s,
                                  float* __restrict__ escore, int Et) {
  int p = blockIdx.x * blockDim.x + threadIdx.x;
  if (p >= Et) return;
  int s = src_s[p], d = dst_s[p];
  float4 a = *(const float4*)(as + (size_t)s * 4);
  float4 b = *(const float4*)(ad + (size_t)d * 4);
  float4 e;
  e.x = leaky(a.x + b.x);
  e.y = leaky(a.y + b.y);
  e.z = leaky(a.z + b.z);
  e.w = leaky(a.w + b.w);
  *(float4*)(escore + (size_t)p * 4) = e;
}

// ---------------- segment softmax + aggregate ----------------
// block = 512 threads, one node per block; thread tid -> head=tid>>7, c=tid&127

template <bool RELU>
__global__ void aggregate_kernel(const float* __restrict__ hsrc, const float* __restrict__ escore,
                                 const int* __restrict__ src_s, const int* __restrict__ off,
                                 const float* __restrict__ bias, float* __restrict__ out) {
  int n = blockIdx.x;
  int tid = threadIdx.x;
  int head = tid >> 7;
  int p0 = off[n], p1 = off[n + 1];
  float m = -1e30f;
  for (int p = p0; p < p1; ++p) m = fmaxf(m, escore[(size_t)p * 4 + head]);
  float denom = 0.f;
  for (int p = p0; p < p1; ++p) denom += __expf(escore[(size_t)p * 4 + head] - m);
  denom += 1e-16f;
  float acc = 0.f;
  for (int p = p0; p < p1; ++p) {
    float alpha = __expf(escore[(size_t)p * 4 + head] - m) / denom;
    int s = src_s[p];
    acc += alpha * hsrc[(size_t)s * F + tid];
  }
  float v = acc + bias[tid];
  if (RELU) v = fmaxf(v, 0.f);
  out[(size_t)n * F + tid] = v;
}

// layer3: one thread per (node, head); reduce 4 heads via shfl
__global__ void aggregate3_kernel(const float* __restrict__ h3, const float* __restrict__ escore,
                                  const int* __restrict__ src_s, const int* __restrict__ off,
                                  const float* __restrict__ b3, float* __restrict__ out, int N) {
  int t = blockIdx.x * blockDim.x + threadIdx.x;
  if (t >= N * 4) return;
  int n = t >> 2, head = t & 3;
  int p0 = off[n], p1 = off[n + 1];
  float m = -1e30f;
  for (int p = p0; p < p1; ++p) m = fmaxf(m, escore[(size_t)p * 4 + head]);
  float denom = 0.f;
  for (int p = p0; p < p1; ++p) denom += __expf(escore[(size_t)p * 4 + head] - m);
  denom += 1e-16f;
  float acc = 0.f;
  for (int p = p0; p < p1; ++p) {
    float alpha = __expf(escore[(size_t)p * 4 + head] - m) / denom;
    acc += alpha * h3[(size_t)src_s[p] * 4 + head];
  }
  acc += __shfl_down(acc, 1);
  acc += __shfl_down(acc, 2);
  if (head == 0) out[n] = acc * 0.25f + b3[0];
}

// ---------------- host orchestration ----------------

extern "C" void kernel_launch(void* const* d_in, const int* in_sizes, int n_in,
                              void* d_out, int out_size, void* d_ws, size_t ws_size,
                              hipStream_t stream) {
  const float* x   = (const float*)d_in[0];
  const int*   ei  = (const int*)d_in[1];
  const float* W1  = (const float*)d_in[2];
  const float* a1s = (const float*)d_in[3];
  const float* a1d = (const float*)d_in[4];
  const float* b1  = (const float*)d_in[5];
  const float* W2  = (const float*)d_in[6];
  const float* a2s = (const float*)d_in[7];
  const float* a2d = (const float*)d_in[8];
  const float* b2  = (const float*)d_in[9];
  const float* W3  = (const float*)d_in[10];
  const float* a3s = (const float*)d_in[11];
  const float* a3d = (const float*)d_in[12];
  const float* b3  = (const float*)d_in[13];

  const int N = in_sizes[0] / F_IN;
  const int E = in_sizes[1] / 2;
  const int Et = E + N;

  char* base = (char*)d_ws;
  size_t off = 0;
  auto alloc = [&](size_t bytes) {
    void* p = base + off;
    off = (off + bytes + 255) & ~(size_t)255;
    return p;
  };
  float* A      = (float*)alloc((size_t)N * F * sizeof(float));
  float* Bbuf   = (float*)alloc((size_t)N * F * sizeof(float));
  float* escore = (float*)alloc((size_t)Et * 4 * sizeof(float));
  int*   src_s  = (int*)alloc((size_t)Et * sizeof(int));
  int*   dst_s  = (int*)alloc((size_t)Et * sizeof(int));
  int*   counts = (int*)alloc((size_t)N * sizeof(int));
  int*   offs   = (int*)alloc((size_t)(N + 1) * sizeof(int));
  int*   cursor = (int*)alloc((size_t)N * sizeof(int));
  float* as     = (float*)alloc((size_t)N * 4 * sizeof(float));
  float* ad     = (float*)alloc((size_t)N * 4 * sizeof(float));
  float* h3     = (float*)alloc((size_t)N * 4 * sizeof(float));

  // ---- CSR build (graph fixed across layers) ----
  hipMemsetAsync(counts, 0, (size_t)N * sizeof(int), stream);
  {
    int g = (Et + 255) / 256;
    hipLaunchKernelGGL(hist_kernel, dim3(g), dim3(256), 0, stream, ei, counts, N, E);
    hipLaunchKernelGGL(scan_kernel, dim3(1), dim3(1024), 0, stream, counts, offs, cursor, N);
    hipLaunchKernelGGL(scatter_kernel, dim3(g), dim3(256), 0, stream, ei, cursor, src_s, dst_s, N, E);
  }

  int gemmGrid = (N + 7) / 8;
  int edgeGrid = (Et + 255) / 256;
  int nhGrid   = (N * 4 + 255) / 256;

  // ---- layer 1 ----
  hipLaunchKernelGGL(gemm_kernel<F_IN>, dim3(gemmGrid), dim3(256), 0, stream, x, W1, A, N);
  hipLaunchKernelGGL(alpha_kernel, dim3(N), dim3(512), 0, stream, A, a1s, a1d, as, ad);
  hipLaunchKernelGGL(edge_score_kernel, dim3(edgeGrid), dim3(256), 0, stream, as, ad, src_s, dst_s, escore, Et);
  hipLaunchKernelGGL((aggregate_kernel<true>), dim3(N), dim3(512), 0, stream, A, escore, src_s, offs, b1, Bbuf);

  // ---- layer 2 ----
  hipLaunchKernelGGL(gemm_kernel<F>, dim3(gemmGrid), dim3(256), 0, stream, Bbuf, W2, A, N);
  hipLaunchKernelGGL(alpha_kernel, dim3(N), dim3(512), 0, stream, A, a2s, a2d, as, ad);
  hipLaunchKernelGGL(edge_score_kernel, dim3(edgeGrid), dim3(256), 0, stream, as, ad, src_s, dst_s, escore, Et);
  hipLaunchKernelGGL((aggregate_kernel<true>), dim3(N), dim3(512), 0, stream, A, escore, src_s, offs, b2, Bbuf);

  // ---- layer 3 ----
  hipLaunchKernelGGL(gemm3_kernel, dim3((N + 3) / 4), dim3(256), 0, stream, Bbuf, W3, h3, N);
  hipLaunchKernelGGL(alpha3_kernel, dim3(nhGrid), dim3(256), 0, stream, h3, a3s, a3d, as, ad, N);
  hipLaunchKernelGGL(edge_score_kernel, dim3(edgeGrid), dim3(256), 0, stream, as, ad, src_s, dst_s, escore, Et);
  hipLaunchKernelGGL(aggregate3_kernel, dim3(nhGrid), dim3(256), 0, stream, h3, escore, src_s, offs, b3, (float*)d_out, N);
}

// Round 4
// 1324.189 us; speedup vs baseline: 1.7013x; 1.7013x over previous
//
#include <hip/hip_runtime.h>

#define NEG_SLOPE 0.2f

constexpr int F = 512;    // heads * channels
constexpr int F_IN = 30;

// ---------------- CSR build ----------------

__global__ void hist_kernel(const int* __restrict__ ei, int* __restrict__ counts,
                            int N, int E) {
  int e = blockIdx.x * blockDim.x + threadIdx.x;
  int Et = E + N;
  if (e >= Et) return;
  int d = (e < E) ? ei[E + e] : (e - E);
  atomicAdd(&counts[d], 1);
}

__global__ void scan_kernel(const int* __restrict__ counts, int* __restrict__ offsets,
                            int* __restrict__ cursor, int n) {
  __shared__ int lds[1024];
  __shared__ int carry_s;
  if (threadIdx.x == 0) carry_s = 0;
  __syncthreads();
  for (int base = 0; base < n; base += 1024) {
    int i = base + threadIdx.x;
    int v = (i < n) ? counts[i] : 0;
    lds[threadIdx.x] = v;
    __syncthreads();
    for (int off = 1; off < 1024; off <<= 1) {
      int t = (threadIdx.x >= off) ? lds[threadIdx.x - off] : 0;
      __syncthreads();
      lds[threadIdx.x] += t;
      __syncthreads();
    }
    int excl = lds[threadIdx.x] - v;
    if (i < n) { int o = carry_s + excl; offsets[i] = o; cursor[i] = o; }
    __syncthreads();
    if (threadIdx.x == 1023) carry_s += lds[1023];
    __syncthreads();
  }
  if (threadIdx.x == 0) offsets[n] = carry_s;
}

__global__ void scatter_kernel(const int* __restrict__ ei, int* __restrict__ cursor,
                               int* __restrict__ src_s, int* __restrict__ dst_s,
                               int N, int E) {
  int e = blockIdx.x * blockDim.x + threadIdx.x;
  int Et = E + N;
  if (e >= Et) return;
  int s, d;
  if (e < E) { s = ei[e]; d = ei[E + e]; } else { s = e - E; d = e - E; }
  int p = atomicAdd(&cursor[d], 1);
  src_s[p] = s;
  dst_s[p] = d;
}

// Canonicalize within-segment order (atomic scatter order is non-deterministic
// across graph replays -> FP sums drift). Sort each node's src list ascending;
// duplicate (dst,src) pairs contribute bit-identical summands, so the result
// is order-invariant. One thread per node, avg degree ~17: insertion sort.
__global__ void segsort_kernel(int* __restrict__ src_s, const int* __restrict__ off, int N) {
  int n = blockIdx.x * blockDim.x + threadIdx.x;
  if (n >= N) return;
  int p0 = off[n], p1 = off[n + 1];
  for (int i = p0 + 1; i < p1; ++i) {
    int key = src_s[i];
    int j = i - 1;
    while (j >= p0 && src_s[j] > key) { src_s[j + 1] = src_s[j]; --j; }
    src_s[j + 1] = key;
  }
}

// ---------------- GEMM:  out[N,512] = X[N,K] @ W[K,512] ----------------
// block = 256 threads; tile = 16 rows x 512 cols; thread -> 8 rows x 4 cols

template <int K>
__global__ void gemm_kernel(const float* __restrict__ X, const float* __restrict__ W,
                            float* __restrict__ out, int N) {
  __shared__ float xs[16][K];
  int row0 = blockIdx.x * 16;
  int tid = threadIdx.x;
  if constexpr (K % 4 == 0) {
    for (int i = tid; i < 16 * K / 4; i += 256) {
      int r = (i * 4) / K, k = (i * 4) % K;
      int row = row0 + r;
      float4 v = make_float4(0.f, 0.f, 0.f, 0.f);
      if (row < N) v = *(const float4*)(X + (size_t)row * K + k);
      *(float4*)(&xs[r][k]) = v;
    }
  } else {
    for (int i = tid; i < 16 * K; i += 256) {
      int r = i / K, k = i - r * K;
      int row = row0 + r;
      xs[r][k] = (row < N) ? X[(size_t)row * K + k] : 0.f;
    }
  }
  __syncthreads();
  int cg = tid & 127;     // 128 col groups of 4
  int rg = tid >> 7;      // 0..1 -> rows rg*8 .. rg*8+7
  int c0 = cg * 4;
  float4 acc[8];
#pragma unroll
  for (int r = 0; r < 8; ++r) acc[r] = make_float4(0.f, 0.f, 0.f, 0.f);
#pragma unroll 4
  for (int k = 0; k < K; ++k) {
    float4 w = *(const float4*)(W + (size_t)k * F + c0);
#pragma unroll
    for (int r = 0; r < 8; ++r) {
      float xv = xs[rg * 8 + r][k];
      acc[r].x += xv * w.x; acc[r].y += xv * w.y;
      acc[r].z += xv * w.z; acc[r].w += xv * w.w;
    }
  }
#pragma unroll
  for (int r = 0; r < 8; ++r) {
    int row = row0 + rg * 8 + r;
    if (row < N) *(float4*)(out + (size_t)row * F + c0) = acc[r];
  }
}

// GEMM for layer3: out[N,4] = X[N,512] @ W3[512,4]; one wave per node
__global__ void gemm3_kernel(const float* __restrict__ X, const float* __restrict__ W3,
                             float* __restrict__ h3, int N) {
  int n = blockIdx.x * 4 + (threadIdx.x >> 6);
  int lane = threadIdx.x & 63;
  if (n >= N) return;
  float acc[4] = {0.f, 0.f, 0.f, 0.f};
  for (int k = lane; k < F; k += 64) {
    float xv = X[(size_t)n * F + k];
#pragma unroll
    for (int j = 0; j < 4; ++j) acc[j] += xv * W3[k * 4 + j];
  }
#pragma unroll
  for (int j = 0; j < 4; ++j)
    for (int off = 32; off > 0; off >>= 1) acc[j] += __shfl_down(acc[j], off);
  if (lane == 0) {
    float4 o; o.x = acc[0]; o.y = acc[1]; o.z = acc[2]; o.w = acc[3];
    *(float4*)(h3 + (size_t)n * 4) = o;
  }
}

// ---------------- alpha dots ----------------
// block = 128 threads = 1 node; thread tid -> channels 4*tid.., head = tid>>5

__global__ void alpha_kernel(const float* __restrict__ h, const float* __restrict__ asrc,
                             const float* __restrict__ adst, float* __restrict__ as,
                             float* __restrict__ ad) {
  int n = blockIdx.x;
  int tid = threadIdx.x;
  int c0 = tid * 4;
  float4 hv = *(const float4*)(h + (size_t)n * F + c0);
  float4 sa = *(const float4*)(asrc + c0);
  float4 da = *(const float4*)(adst + c0);
  float ps = hv.x * sa.x + hv.y * sa.y + hv.z * sa.z + hv.w * sa.w;
  float pd = hv.x * da.x + hv.y * da.y + hv.z * da.z + hv.w * da.w;
#pragma unroll
  for (int off = 16; off > 0; off >>= 1) {
    ps += __shfl_down(ps, off);
    pd += __shfl_down(pd, off);
  }
  if ((tid & 31) == 0) {
    int head = tid >> 5;
    as[n * 4 + head] = ps;
    ad[n * 4 + head] = pd;
  }
}

// layer3: C=1 -> as[n,h] = h3[n,h]*a3s[h]
__global__ void alpha3_kernel(const float* __restrict__ h3, const float* __restrict__ a3s,
                              const float* __restrict__ a3d, float* __restrict__ as,
                              float* __restrict__ ad, int N) {
  int t = blockIdx.x * blockDim.x + threadIdx.x;
  if (t >= N * 4) return;
  int hh = t & 3;
  float v = h3[t];
  as[t] = v * a3s[hh];
  ad[t] = v * a3d[hh];
}

// ---------------- edge scores (sorted order) ----------------

__device__ __forceinline__ float leaky(float v) { return v > 0.f ? v : NEG_SLOPE * v; }

__global__ void edge_score_kernel(const float* __restrict__ as, const float* __restrict__ ad,
                                  const int* __restrict__ src_s, const int* __restrict__ dst_s,
                                  float* __restrict__ escore, int Et) {
  int p = blockIdx.x * blockDim.x + threadIdx.x;
  if (p >= Et) return;
  int s = src_s[p], d = dst_s[p];
  float4 a = *(const float4*)(as + (size_t)s * 4);
  float4 b = *(const float4*)(ad + (size_t)d * 4);
  float4 e;
  e.x = leaky(a.x + b.x);
  e.y = leaky(a.y + b.y);
  e.z = leaky(a.z + b.z);
  e.w = leaky(a.w + b.w);
  *(float4*)(escore + (size_t)p * 4) = e;
}

// ---------------- segment softmax: stats then normalize ----------------
// one thread per (node, head); online max+sum in a single pass

__global__ void softmax_stats_kernel(const float* __restrict__ escore, const int* __restrict__ off,
                                     float* __restrict__ m_out, float* __restrict__ d_out_, int N) {
  int t = blockIdx.x * blockDim.x + threadIdx.x;
  if (t >= N * 4) return;
  int n = t >> 2, h = t & 3;
  int p0 = off[n], p1 = off[n + 1];
  float m = -1e30f, s = 0.f;
  for (int p = p0; p < p1; ++p) {
    float e = escore[(size_t)p * 4 + h];
    if (e > m) { s *= __expf(m - e); m = e; }
    s += __expf(e - m);
  }
  m_out[t] = m;
  d_out_[t] = s + 1e-16f;
}

__global__ void alpha_norm_kernel(float* __restrict__ escore, const int* __restrict__ dst_s,
                                  const float* __restrict__ m, const float* __restrict__ denom,
                                  int Et) {
  int p = blockIdx.x * blockDim.x + threadIdx.x;
  if (p >= Et) return;
  int d = dst_s[p];
  float4 e = *(const float4*)(escore + (size_t)p * 4);
  float4 mm = *(const float4*)(m + (size_t)d * 4);
  float4 dd = *(const float4*)(denom + (size_t)d * 4);
  e.x = __expf(e.x - mm.x) / dd.x;
  e.y = __expf(e.y - mm.y) / dd.y;
  e.z = __expf(e.z - mm.z) / dd.z;
  e.w = __expf(e.w - mm.w) / dd.w;
  *(float4*)(escore + (size_t)p * 4) = e;
}

// ---------------- aggregate: single pass, float4 ----------------
// block = 128 threads, one node per block; thread tid -> channels 4*tid..

template <bool RELU>
__global__ void aggregate_kernel(const float* __restrict__ hsrc, const float* __restrict__ alpha,
                                 const int* __restrict__ src_s, const int* __restrict__ off,
                                 const float* __restrict__ bias, float* __restrict__ out) {
  int n = blockIdx.x;
  int tid = threadIdx.x;
  int c0 = tid * 4;
  int head = tid >> 5;
  int p0 = off[n], p1 = off[n + 1];
  float4 acc = make_float4(0.f, 0.f, 0.f, 0.f);
  for (int p = p0; p < p1; ++p) {
    float a = alpha[(size_t)p * 4 + head];
    int s = src_s[p];
    float4 hv = *(const float4*)(hsrc + (size_t)s * F + c0);
    acc.x += a * hv.x; acc.y += a * hv.y;
    acc.z += a * hv.z; acc.w += a * hv.w;
  }
  float4 bv = *(const float4*)(bias + c0);
  acc.x += bv.x; acc.y += bv.y; acc.z += bv.z; acc.w += bv.w;
  if (RELU) {
    acc.x = fmaxf(acc.x, 0.f); acc.y = fmaxf(acc.y, 0.f);
    acc.z = fmaxf(acc.z, 0.f); acc.w = fmaxf(acc.w, 0.f);
  }
  *(float4*)(out + (size_t)n * F + c0) = acc;
}

// layer3: one thread per (node, head); single pass; reduce 4 heads via shfl
__global__ void aggregate3_kernel(const float* __restrict__ h3, const float* __restrict__ alpha,
                                  const int* __restrict__ src_s, const int* __restrict__ off,
                                  const float* __restrict__ b3, float* __restrict__ out, int N) {
  int t = blockIdx.x * blockDim.x + threadIdx.x;
  if (t >= N * 4) return;
  int n = t >> 2, head = t & 3;
  int p0 = off[n], p1 = off[n + 1];
  float acc = 0.f;
  for (int p = p0; p < p1; ++p)
    acc += alpha[(size_t)p * 4 + head] * h3[(size_t)src_s[p] * 4 + head];
  acc += __shfl_down(acc, 1);
  acc += __shfl_down(acc, 2);
  if (head == 0) out[n] = acc * 0.25f + b3[0];
}

// ---------------- host orchestration ----------------

extern "C" void kernel_launch(void* const* d_in, const int* in_sizes, int n_in,
                              void* d_out, int out_size, void* d_ws, size_t ws_size,
                              hipStream_t stream) {
  const float* x   = (const float*)d_in[0];
  const int*   ei  = (const int*)d_in[1];
  const float* W1  = (const float*)d_in[2];
  const float* a1s = (const float*)d_in[3];
  const float* a1d = (const float*)d_in[4];
  const float* b1  = (const float*)d_in[5];
  const float* W2  = (const float*)d_in[6];
  const float* a2s = (const float*)d_in[7];
  const float* a2d = (const float*)d_in[8];
  const float* b2  = (const float*)d_in[9];
  const float* W3  = (const float*)d_in[10];
  const float* a3s = (const float*)d_in[11];
  const float* a3d = (const float*)d_in[12];
  const float* b3  = (const float*)d_in[13];

  const int N = in_sizes[0] / F_IN;
  const int E = in_sizes[1] / 2;
  const int Et = E + N;

  char* base = (char*)d_ws;
  size_t off = 0;
  auto alloc = [&](size_t bytes) {
    void* p = base + off;
    off = (off + bytes + 255) & ~(size_t)255;
    return p;
  };
  float* A      = (float*)alloc((size_t)N * F * sizeof(float));
  float* Bbuf   = (float*)alloc((size_t)N * F * sizeof(float));
  float* escore = (float*)alloc((size_t)Et * 4 * sizeof(float));
  int*   src_s  = (int*)alloc((size_t)Et * sizeof(int));
  int*   dst_s  = (int*)alloc((size_t)Et * sizeof(int));
  int*   counts = (int*)alloc((size_t)N * sizeof(int));
  int*   offs   = (int*)alloc((size_t)(N + 1) * sizeof(int));
  int*   cursor = (int*)alloc((size_t)N * sizeof(int));
  float* as     = (float*)alloc((size_t)N * 4 * sizeof(float));
  float* ad     = (float*)alloc((size_t)N * 4 * sizeof(float));
  float* m_buf  = (float*)alloc((size_t)N * 4 * sizeof(float));
  float* d_buf  = (float*)alloc((size_t)N * 4 * sizeof(float));
  float* h3     = (float*)alloc((size_t)N * 4 * sizeof(float));

  // ---- CSR build (graph fixed across layers) ----
  hipMemsetAsync(counts, 0, (size_t)N * sizeof(int), stream);
  {
    int g = (Et + 255) / 256;
    hipLaunchKernelGGL(hist_kernel, dim3(g), dim3(256), 0, stream, ei, counts, N, E);
    hipLaunchKernelGGL(scan_kernel, dim3(1), dim3(1024), 0, stream, counts, offs, cursor, N);
    hipLaunchKernelGGL(scatter_kernel, dim3(g), dim3(256), 0, stream, ei, cursor, src_s, dst_s, N, E);
    hipLaunchKernelGGL(segsort_kernel, dim3((N + 255) / 256), dim3(256), 0, stream, src_s, offs, N);
  }

  int gemmGrid = (N + 15) / 16;
  int edgeGrid = (Et + 255) / 256;
  int nhGrid   = (N * 4 + 255) / 256;

  // ---- layer 1 ----
  hipLaunchKernelGGL(gemm_kernel<F_IN>, dim3(gemmGrid), dim3(256), 0, stream, x, W1, A, N);
  hipLaunchKernelGGL(alpha_kernel, dim3(N), dim3(128), 0, stream, A, a1s, a1d, as, ad);
  hipLaunchKernelGGL(edge_score_kernel, dim3(edgeGrid), dim3(256), 0, stream, as, ad, src_s, dst_s, escore, Et);
  hipLaunchKernelGGL(softmax_stats_kernel, dim3(nhGrid), dim3(256), 0, stream, escore, offs, m_buf, d_buf, N);
  hipLaunchKernelGGL(alpha_norm_kernel, dim3(edgeGrid), dim3(256), 0, stream, escore, dst_s, m_buf, d_buf, Et);
  hipLaunchKernelGGL((aggregate_kernel<true>), dim3(N), dim3(128), 0, stream, A, escore, src_s, offs, b1, Bbuf);

  // ---- layer 2 ----
  hipLaunchKernelGGL(gemm_kernel<F>, dim3(gemmGrid), dim3(256), 0, stream, Bbuf, W2, A, N);
  hipLaunchKernelGGL(alpha_kernel, dim3(N), dim3(128), 0, stream, A, a2s, a2d, as, ad);
  hipLaunchKernelGGL(edge_score_kernel, dim3(edgeGrid), dim3(256), 0, stream, as, ad, src_s, dst_s, escore, Et);
  hipLaunchKernelGGL(softmax_stats_kernel, dim3(nhGrid), dim3(256), 0, stream, escore, offs, m_buf, d_buf, N);
  hipLaunchKernelGGL(alpha_norm_kernel, dim3(edgeGrid), dim3(256), 0, stream, escore, dst_s, m_buf, d_buf, Et);
  hipLaunchKernelGGL((aggregate_kernel<true>), dim3(N), dim3(128), 0, stream, A, escore, src_s, offs, b2, Bbuf);

  // ---- layer 3 ----
  hipLaunchKernelGGL(gemm3_kernel, dim3((N + 3) / 4), dim3(256), 0, stream, Bbuf, W3, h3, N);
  hipLaunchKernelGGL(alpha3_kernel, dim3(nhGrid), dim3(256), 0, stream, h3, a3s, a3d, as, ad, N);
  hipLaunchKernelGGL(edge_score_kernel, dim3(edgeGrid), dim3(256), 0, stream, as, ad, src_s, dst_s, escore, Et);
  hipLaunchKernelGGL(softmax_stats_kernel, dim3(nhGrid), dim3(256), 0, stream, escore, offs, m_buf, d_buf, N);
  hipLaunchKernelGGL(alpha_norm_kernel, dim3(edgeGrid), dim3(256), 0, stream, escore, dst_s, m_buf, d_buf, Et);
  hipLaunchKernelGGL(aggregate3_kernel, dim3(nhGrid), dim3(256), 0, stream, h3, escore, src_s, offs, b3, (float*)d_out, N);
}